// Round 1
// baseline (501.676 us; speedup 1.0000x reference)
//
#include <hip/hip_runtime.h>
#include <cstdint>
#include <cmath>

#define HID 768
#define INNER 1536
#define NST 16
#define SEQ 2048
#define BATCH 2
#define MTOK 4096      // BATCH*SEQ
#define CHUNK 128
#define NCHUNK 16      // SEQ/CHUNK
#define LOG2E 1.44269504088896f

typedef unsigned short u16;
typedef __bf16 bf16x8 __attribute__((ext_vector_type(8)));
typedef float f32x4 __attribute__((ext_vector_type(4)));

__device__ __forceinline__ u16 f2b(float f) {
  union { float f; unsigned u; } a; a.f = f;
  unsigned r = a.u + 0x7FFFu + ((a.u >> 16) & 1u);
  return (u16)(r >> 16);
}

__device__ __forceinline__ void gl2lds16(const u16* g, u16* l) {
  __builtin_amdgcn_global_load_lds(
      (const __attribute__((address_space(1))) void*)g,
      (__attribute__((address_space(3))) void*)l, 16, 0, 0);
}

// ---------------- LayerNorm + cast to bf16 ----------------
__global__ __launch_bounds__(256)
void ln_kernel(const float* __restrict__ x, const float* __restrict__ w,
               const float* __restrict__ b, u16* __restrict__ xn) {
  const long row = blockIdx.x;
  const float* xr = x + row * HID;
  const int t = threadIdx.x;
  float v0 = xr[t], v1 = xr[t + 256], v2 = xr[t + 512];
  float s1 = v0 + v1 + v2;
  float s2 = v0 * v0 + v1 * v1 + v2 * v2;
#pragma unroll
  for (int o = 32; o > 0; o >>= 1) { s1 += __shfl_down(s1, o); s2 += __shfl_down(s2, o); }
  __shared__ float r1[4], r2[4];
  if ((t & 63) == 0) { r1[t >> 6] = s1; r2[t >> 6] = s2; }
  __syncthreads();
  s1 = r1[0] + r1[1] + r1[2] + r1[3];
  s2 = r2[0] + r2[1] + r2[2] + r2[3];
  const float mu = s1 * (1.f / HID);
  float var = s2 * (1.f / HID) - mu * mu;
  const float rs = rsqrtf(var + 1e-5f);
  xn[row * HID + t]       = f2b((v0 - mu) * rs * w[t]       + b[t]);
  xn[row * HID + t + 256] = f2b((v1 - mu) * rs * w[t + 256] + b[t + 256]);
  xn[row * HID + t + 512] = f2b((v2 - mu) * rs * w[t + 512] + b[t + 512]);
}

// ---------------- fp32 W[K][N] -> bf16 Wt[Npad][K] (transpose+convert, zero pad) ----
__global__ __launch_bounds__(256)
void transpose_cvt(const float* __restrict__ W, u16* __restrict__ Wt,
                   int K, int N, int Npad) {
  __shared__ float tb[32][33];
  const int tx = threadIdx.x, ty = threadIdx.y;
  const int n0 = blockIdx.x * 32, k0 = blockIdx.y * 32;
#pragma unroll
  for (int r = 0; r < 4; ++r) {
    int kk = k0 + ty + r * 8;
    int nn = n0 + tx;
    tb[ty + r * 8][tx] = (nn < N) ? W[(long)kk * N + nn] : 0.f;
  }
  __syncthreads();
#pragma unroll
  for (int r = 0; r < 4; ++r) {
    int nn = n0 + ty + r * 8;
    int kk = k0 + tx;
    Wt[(long)nn * K + kk] = f2b(tb[tx][ty + r * 8]);
  }
}

// ---------------- GEMM: A[M][K] bf16 row-major, Bt[N][K] bf16, 128x128 tile ------
// EPI 0: C0[row*3072+col] = v                      (xp)
// EPI 1: col<16 -> Bm, col<32 -> Cm, col<Nstore -> delta=softplus
// EPI 2: zb = bf16(v * silu(gate)), gate = E0[row*3072+1536+col]
// EPI 3: C0[row*768+col] = v + E0[row*768+col]     (final out + residual)
template <int EPI>
__global__ __launch_bounds__(256)
void gemm_bt(const u16* __restrict__ A, const u16* __restrict__ Bt,
             float* __restrict__ C0, float* __restrict__ C1, float* __restrict__ C2,
             u16* __restrict__ Cb, const float* __restrict__ E0,
             int K, int Nstore) {
  __shared__ u16 As[128 * 32];
  __shared__ u16 Bs[128 * 32];
  const int tid = threadIdx.x;
  const int lane = tid & 63;
  const int wave = tid >> 6;
  const int wm = wave >> 1, wn = wave & 1;
  const int l16 = lane & 15, l4 = lane >> 4;
  const long bm = (long)blockIdx.y * 128;
  const long bn = (long)blockIdx.x * 128;

  f32x4 acc[4][4] = {};

  const int r0 = tid >> 2;
  const int kg = (tid & 3) * 8;
  const u16* Ap0 = A + (bm + r0) * K + kg;
  const u16* Ap1 = A + (bm + r0 + 64) * K + kg;
  const u16* Bp0 = Bt + (bn + r0) * K + kg;
  const u16* Bp1 = Bt + (bn + r0 + 64) * K + kg;
  u16* As0 = As + tid * 8;
  u16* As1 = As + (256 + tid) * 8;
  u16* Bs0 = Bs + tid * 8;
  u16* Bs1 = Bs + (256 + tid) * 8;

  for (int k0 = 0; k0 < K; k0 += 32) {
    gl2lds16(Ap0 + k0, As0);
    gl2lds16(Ap1 + k0, As1);
    gl2lds16(Bp0 + k0, Bs0);
    gl2lds16(Bp1 + k0, Bs1);
    __syncthreads();
    bf16x8 af[4], bfr[4];
#pragma unroll
    for (int i = 0; i < 4; ++i) {
      af[i]  = *(const bf16x8*)&As[(wm * 64 + i * 16 + l16) * 32 + l4 * 8];
      bfr[i] = *(const bf16x8*)&Bs[(wn * 64 + i * 16 + l16) * 32 + l4 * 8];
    }
#pragma unroll
    for (int i = 0; i < 4; ++i)
#pragma unroll
      for (int j = 0; j < 4; ++j)
        acc[i][j] = __builtin_amdgcn_mfma_f32_16x16x32_bf16(af[i], bfr[j], acc[i][j], 0, 0, 0);
    __syncthreads();
  }

#pragma unroll
  for (int i = 0; i < 4; ++i) {
    const long rr = bm + wm * 64 + i * 16 + l4 * 4;
#pragma unroll
    for (int j = 0; j < 4; ++j) {
      const int cc = (int)bn + wn * 64 + j * 16 + l16;
#pragma unroll
      for (int r = 0; r < 4; ++r) {
        const long row = rr + r;
        const float v = acc[i][j][r];
        if (EPI == 0) {
          C0[row * 3072 + cc] = v;
        } else if (EPI == 1) {
          if (cc < 16) C0[row * 16 + cc] = v;
          else if (cc < 32) C1[row * 16 + (cc - 16)] = v;
          else if (cc < Nstore) {
            float sp = (v > 20.f) ? v : log1pf(__expf(v));
            C2[row * 1536 + (cc - 32)] = sp;
          }
        } else if (EPI == 2) {
          float g = E0[row * 3072 + 1536 + cc];
          float s = g / (1.f + __expf(-g));
          Cb[row * 1536 + cc] = f2b(v * s);
        } else {
          C0[row * 768 + cc] = v + E0[row * 768 + cc];
        }
      }
    }
  }
}

// ---------------- depthwise causal conv(K=4) + SiLU ----------------
__global__ __launch_bounds__(256)
void conv_silu(const float* __restrict__ xp, const float* __restrict__ cw,
               float* __restrict__ uf, u16* __restrict__ ub) {
  const int c = blockIdx.x * 256 + threadIdx.x;
  const long m = blockIdx.y;
  const int t = (int)(m & (SEQ - 1));
  const float w0 = cw[c * 4 + 0], w1 = cw[c * 4 + 1], w2 = cw[c * 4 + 2], w3 = cw[c * 4 + 3];
  float acc = w3 * xp[m * 3072 + c];
  if (t >= 1) acc += w2 * xp[(m - 1) * 3072 + c];
  if (t >= 2) acc += w1 * xp[(m - 2) * 3072 + c];
  if (t >= 3) acc += w0 * xp[(m - 3) * 3072 + c];
  const float s = acc / (1.f + __expf(-acc));
  uf[m * 1536 + c] = s;
  ub[m * 1536 + c] = f2b(s);
}

// ---------------- scan phase A: per-chunk (P, Q) from h=0 ----------------
__global__ __launch_bounds__(256)
void scan_phaseA(const float* __restrict__ dlt, const float* __restrict__ uf,
                 const float* __restrict__ Bm, const float* __restrict__ A_log,
                 float* __restrict__ P, float* __restrict__ Q) {
  const int c = blockIdx.x * 256 + threadIdx.x;
  const int b = blockIdx.y;
  const int ch = blockIdx.z;
  float a2[NST];
#pragma unroll
  for (int n = 0; n < NST; ++n) a2[n] = -__expf(A_log[n]) * LOG2E;
  float h[NST];
#pragma unroll
  for (int n = 0; n < NST; ++n) h[n] = 0.f;
  float sumd = 0.f;
  const long base = (long)b * SEQ + (long)ch * CHUNK;
  for (int t = 0; t < CHUNK; ++t) {
    const long m = base + t;
    const float d = dlt[m * 1536 + c];
    const float du = d * uf[m * 1536 + c];
    sumd += d;
    const float* Bp = Bm + m * 16;
#pragma unroll
    for (int n = 0; n < NST; ++n) {
      const float e = exp2f(a2[n] * d);
      h[n] = e * h[n] + du * Bp[n];
    }
  }
  const long sb = (((long)b * NCHUNK + ch) * NST) * 1536 + c;
#pragma unroll
  for (int n = 0; n < NST; ++n) {
    Q[sb + (long)n * 1536] = h[n];
    P[sb + (long)n * 1536] = exp2f(a2[n] * sumd);
  }
}

// ---------------- scan phase B: serial combine over chunks ----------------
__global__ __launch_bounds__(256)
void scan_phaseB(const float* __restrict__ P, const float* __restrict__ Q,
                 float* __restrict__ hs) {
  const long g = (long)blockIdx.x * 256 + threadIdx.x;   // 2*16*1536
  const int c = (int)(g % 1536);
  const int n = (int)((g / 1536) % NST);
  const int b = (int)(g / (1536 * NST));
  float h = 0.f;
  for (int ch = 0; ch < NCHUNK; ++ch) {
    const long idx = (((long)b * NCHUNK + ch) * NST + n) * 1536 + c;
    hs[idx] = h;
    h = P[idx] * h + Q[idx];
  }
}

// ---------------- scan phase C: replay with true h_start, emit ys bf16 --------
__global__ __launch_bounds__(256)
void scan_phaseC(const float* __restrict__ dlt, const float* __restrict__ uf,
                 const float* __restrict__ Bm, const float* __restrict__ Cm,
                 const float* __restrict__ A_log, const float* __restrict__ Dv,
                 const float* __restrict__ hs, u16* __restrict__ ys) {
  const int c = blockIdx.x * 256 + threadIdx.x;
  const int b = blockIdx.y;
  const int ch = blockIdx.z;
  float a2[NST];
#pragma unroll
  for (int n = 0; n < NST; ++n) a2[n] = -__expf(A_log[n]) * LOG2E;
  float h[NST];
  const long sb = (((long)b * NCHUNK + ch) * NST) * 1536 + c;
#pragma unroll
  for (int n = 0; n < NST; ++n) h[n] = hs[sb + (long)n * 1536];
  const float Dc = Dv[c];
  const long base = (long)b * SEQ + (long)ch * CHUNK;
  for (int t = 0; t < CHUNK; ++t) {
    const long m = base + t;
    const float d = dlt[m * 1536 + c];
    const float uu = uf[m * 1536 + c];
    const float du = d * uu;
    const float* Bp = Bm + m * 16;
    const float* Cp = Cm + m * 16;
    float y = Dc * uu;
#pragma unroll
    for (int n = 0; n < NST; ++n) {
      const float e = exp2f(a2[n] * d);
      h[n] = e * h[n] + du * Bp[n];
      y += h[n] * Cp[n];
    }
    ys[m * 1536 + c] = f2b(y);
  }
}

extern "C" void kernel_launch(void* const* d_in, const int* in_sizes, int n_in,
                              void* d_out, int out_size, void* d_ws, size_t ws_size,
                              hipStream_t stream) {
  const float* x     = (const float*)d_in[0];
  const float* nw    = (const float*)d_in[1];
  const float* nb    = (const float*)d_in[2];
  const float* W_in  = (const float*)d_in[3];
  const float* cw    = (const float*)d_in[4];
  const float* W_xp  = (const float*)d_in[5];
  const float* A_log = (const float*)d_in[6];
  const float* Dv    = (const float*)d_in[7];
  const float* W_so  = (const float*)d_in[8];
  const float* W_out = (const float*)d_in[9];
  float* out = (float*)d_out;

  char* w = (char*)d_ws;
  auto alloc = [&](size_t bytes) {
    char* p = w;
    w += (bytes + 255) & ~(size_t)255;
    return p;
  };
  u16*   xn    = (u16*)  alloc((size_t)MTOK * HID * 2);
  u16*   WtIn  = (u16*)  alloc((size_t)3072 * 768 * 2);
  float* xp    = (float*)alloc((size_t)MTOK * 3072 * 4);
  float* uf    = (float*)alloc((size_t)MTOK * 1536 * 4);
  u16*   ub    = (u16*)  alloc((size_t)MTOK * 1536 * 2);
  u16*   WtXp  = (u16*)  alloc((size_t)1664 * 1536 * 2);
  float* Bmv   = (float*)alloc((size_t)MTOK * 16 * 4);
  float* Cmv   = (float*)alloc((size_t)MTOK * 16 * 4);
  float* dlt   = (float*)alloc((size_t)MTOK * 1536 * 4);
  float* P     = (float*)alloc((size_t)BATCH * NCHUNK * NST * 1536 * 4);
  float* Q     = (float*)alloc((size_t)BATCH * NCHUNK * NST * 1536 * 4);
  float* hs    = (float*)alloc((size_t)BATCH * NCHUNK * NST * 1536 * 4);
  u16*   ys    = (u16*)  alloc((size_t)MTOK * 1536 * 2);
  u16*   WtSo  = (u16*)  alloc((size_t)1536 * 1536 * 2);
  u16*   zb    = (u16*)  alloc((size_t)MTOK * 1536 * 2);
  u16*   WtOut = (u16*)  alloc((size_t)768 * 1536 * 2);

  ln_kernel<<<MTOK, 256, 0, stream>>>(x, nw, nb, xn);
  transpose_cvt<<<dim3(3072 / 32, 768 / 32), dim3(32, 8), 0, stream>>>(W_in, WtIn, 768, 3072, 3072);
  transpose_cvt<<<dim3(1664 / 32, 1536 / 32), dim3(32, 8), 0, stream>>>(W_xp, WtXp, 1536, 1568, 1664);
  transpose_cvt<<<dim3(1536 / 32, 1536 / 32), dim3(32, 8), 0, stream>>>(W_so, WtSo, 1536, 1536, 1536);
  transpose_cvt<<<dim3(768 / 32, 1536 / 32), dim3(32, 8), 0, stream>>>(W_out, WtOut, 1536, 768, 768);

  gemm_bt<0><<<dim3(24, 32), 256, 0, stream>>>(xn, WtIn, xp, nullptr, nullptr, nullptr, nullptr, 768, 3072);
  conv_silu<<<dim3(6, MTOK), 256, 0, stream>>>(xp, cw, uf, ub);
  gemm_bt<1><<<dim3(13, 32), 256, 0, stream>>>(ub, WtXp, Bmv, Cmv, dlt, nullptr, nullptr, 1536, 1568);
  scan_phaseA<<<dim3(6, 2, 16), 256, 0, stream>>>(dlt, uf, Bmv, A_log, P, Q);
  scan_phaseB<<<192, 256, 0, stream>>>(P, Q, hs);
  scan_phaseC<<<dim3(6, 2, 16), 256, 0, stream>>>(dlt, uf, Bmv, Cmv, A_log, Dv, hs, ys);
  gemm_bt<2><<<dim3(12, 32), 256, 0, stream>>>(ys, WtSo, nullptr, nullptr, nullptr, zb, xp, 1536, 1536);
  gemm_bt<3><<<dim3(6, 32), 256, 0, stream>>>(zb, WtOut, out, nullptr, nullptr, nullptr, x, 1536, 768);
}

// Round 2
// 420.253 us; speedup vs baseline: 1.1937x; 1.1937x over previous
//
#include <hip/hip_runtime.h>
#include <cstdint>
#include <cmath>

#define HID 768
#define INNER 1536
#define NST 16
#define SEQ 2048
#define BATCH 2
#define MTOK 4096      // BATCH*SEQ
#define CHUNK 32
#define NCHUNK 64      // SEQ/CHUNK
#define LOG2E 1.44269504088896f

typedef unsigned short u16;
typedef __bf16 bf16x8 __attribute__((ext_vector_type(8)));
typedef float f32x4 __attribute__((ext_vector_type(4)));

__device__ __forceinline__ u16 f2b(float f) {
  union { float f; unsigned u; } a; a.f = f;
  unsigned r = a.u + 0x7FFFu + ((a.u >> 16) & 1u);
  return (u16)(r >> 16);
}

__device__ __forceinline__ void gl2lds16(const u16* g, u16* l) {
  __builtin_amdgcn_global_load_lds(
      (const __attribute__((address_space(1))) void*)g,
      (__attribute__((address_space(3))) void*)l, 16, 0, 0);
}

// ---------------- LayerNorm + cast to bf16 ----------------
__global__ __launch_bounds__(256)
void ln_kernel(const float* __restrict__ x, const float* __restrict__ w,
               const float* __restrict__ b, u16* __restrict__ xn) {
  const long row = blockIdx.x;
  const float* xr = x + row * HID;
  const int t = threadIdx.x;
  float v0 = xr[t], v1 = xr[t + 256], v2 = xr[t + 512];
  float s1 = v0 + v1 + v2;
  float s2 = v0 * v0 + v1 * v1 + v2 * v2;
#pragma unroll
  for (int o = 32; o > 0; o >>= 1) { s1 += __shfl_down(s1, o); s2 += __shfl_down(s2, o); }
  __shared__ float r1[4], r2[4];
  if ((t & 63) == 0) { r1[t >> 6] = s1; r2[t >> 6] = s2; }
  __syncthreads();
  s1 = r1[0] + r1[1] + r1[2] + r1[3];
  s2 = r2[0] + r2[1] + r2[2] + r2[3];
  const float mu = s1 * (1.f / HID);
  float var = s2 * (1.f / HID) - mu * mu;
  const float rs = rsqrtf(var + 1e-5f);
  xn[row * HID + t]       = f2b((v0 - mu) * rs * w[t]       + b[t]);
  xn[row * HID + t + 256] = f2b((v1 - mu) * rs * w[t + 256] + b[t + 256]);
  xn[row * HID + t + 512] = f2b((v2 - mu) * rs * w[t + 512] + b[t + 512]);
}

// ---------------- fp32 W[K][N] -> bf16 Wt[Npad][K] (transpose+convert, zero pad) ----
__global__ __launch_bounds__(256)
void transpose_cvt(const float* __restrict__ W, u16* __restrict__ Wt,
                   int K, int N, int Npad) {
  __shared__ float tb[32][33];
  const int tx = threadIdx.x, ty = threadIdx.y;
  const int n0 = blockIdx.x * 32, k0 = blockIdx.y * 32;
#pragma unroll
  for (int r = 0; r < 4; ++r) {
    int kk = k0 + ty + r * 8;
    int nn = n0 + tx;
    tb[ty + r * 8][tx] = (nn < N) ? W[(long)kk * N + nn] : 0.f;
  }
  __syncthreads();
#pragma unroll
  for (int r = 0; r < 4; ++r) {
    int nn = n0 + ty + r * 8;
    int kk = k0 + tx;
    Wt[(long)nn * K + kk] = f2b(tb[tx][ty + r * 8]);
  }
}

// ---------------- GEMM: A[M][K] bf16 row-major, Bt[N][K] bf16, 128x128 tile ------
template <int EPI>
__global__ __launch_bounds__(256)
void gemm_bt(const u16* __restrict__ A, const u16* __restrict__ Bt,
             float* __restrict__ C0, float* __restrict__ C1, float* __restrict__ C2,
             u16* __restrict__ Cb, const float* __restrict__ E0,
             int K, int Nstore) {
  __shared__ u16 As[128 * 32];
  __shared__ u16 Bs[128 * 32];
  const int tid = threadIdx.x;
  const int lane = tid & 63;
  const int wave = tid >> 6;
  const int wm = wave >> 1, wn = wave & 1;
  const int l16 = lane & 15, l4 = lane >> 4;
  const long bm = (long)blockIdx.y * 128;
  const long bn = (long)blockIdx.x * 128;

  f32x4 acc[4][4] = {};

  const int r0 = tid >> 2;
  const int kg = (tid & 3) * 8;
  const u16* Ap0 = A + (bm + r0) * K + kg;
  const u16* Ap1 = A + (bm + r0 + 64) * K + kg;
  const u16* Bp0 = Bt + (bn + r0) * K + kg;
  const u16* Bp1 = Bt + (bn + r0 + 64) * K + kg;
  u16* As0 = As + tid * 8;
  u16* As1 = As + (256 + tid) * 8;
  u16* Bs0 = Bs + tid * 8;
  u16* Bs1 = Bs + (256 + tid) * 8;

  for (int k0 = 0; k0 < K; k0 += 32) {
    gl2lds16(Ap0 + k0, As0);
    gl2lds16(Ap1 + k0, As1);
    gl2lds16(Bp0 + k0, Bs0);
    gl2lds16(Bp1 + k0, Bs1);
    __syncthreads();
    bf16x8 af[4], bfr[4];
#pragma unroll
    for (int i = 0; i < 4; ++i) {
      af[i]  = *(const bf16x8*)&As[(wm * 64 + i * 16 + l16) * 32 + l4 * 8];
      bfr[i] = *(const bf16x8*)&Bs[(wn * 64 + i * 16 + l16) * 32 + l4 * 8];
    }
#pragma unroll
    for (int i = 0; i < 4; ++i)
#pragma unroll
      for (int j = 0; j < 4; ++j)
        acc[i][j] = __builtin_amdgcn_mfma_f32_16x16x32_bf16(af[i], bfr[j], acc[i][j], 0, 0, 0);
    __syncthreads();
  }

#pragma unroll
  for (int i = 0; i < 4; ++i) {
    const long rr = bm + wm * 64 + i * 16 + l4 * 4;
#pragma unroll
    for (int j = 0; j < 4; ++j) {
      const int cc = (int)bn + wn * 64 + j * 16 + l16;
#pragma unroll
      for (int r = 0; r < 4; ++r) {
        const long row = rr + r;
        const float v = acc[i][j][r];
        if (EPI == 0) {
          C0[row * 3072 + cc] = v;
        } else if (EPI == 1) {
          if (cc < 16) C0[row * 16 + cc] = v;
          else if (cc < 32) C1[row * 16 + (cc - 16)] = v;
          else if (cc < Nstore) {
            float sp = (v > 20.f) ? v : log1pf(__expf(v));
            C2[row * 1536 + (cc - 32)] = sp;
          }
        } else if (EPI == 2) {
          float g = E0[row * 3072 + 1536 + cc];
          float s = g / (1.f + __expf(-g));
          Cb[row * 1536 + cc] = f2b(v * s);
        } else {
          C0[row * 768 + cc] = v + E0[row * 768 + cc];
        }
      }
    }
  }
}

// ---------------- depthwise causal conv(K=4) + SiLU ----------------
__global__ __launch_bounds__(256)
void conv_silu(const float* __restrict__ xp, const float* __restrict__ cw,
               float* __restrict__ uf, u16* __restrict__ ub) {
  const int c = blockIdx.x * 256 + threadIdx.x;
  const long m = blockIdx.y;
  const int t = (int)(m & (SEQ - 1));
  const float w0 = cw[c * 4 + 0], w1 = cw[c * 4 + 1], w2 = cw[c * 4 + 2], w3 = cw[c * 4 + 3];
  float acc = w3 * xp[m * 3072 + c];
  if (t >= 1) acc += w2 * xp[(m - 1) * 3072 + c];
  if (t >= 2) acc += w1 * xp[(m - 2) * 3072 + c];
  if (t >= 3) acc += w0 * xp[(m - 3) * 3072 + c];
  const float s = acc / (1.f + __expf(-acc));
  uf[m * 1536 + c] = s;
  ub[m * 1536 + c] = f2b(s);
}

// ---------------- scan phase A: per-chunk (P, Q) from h=0, 4 states/thread ------
// block: 256 threads = 64 channels x 4 state-groups. grid (INNER/64, BATCH, NCHUNK)
__global__ __launch_bounds__(256)
void scan_phaseA(const float* __restrict__ dlt, const float* __restrict__ uf,
                 const float* __restrict__ Bm, const float* __restrict__ A_log,
                 float* __restrict__ P, float* __restrict__ Q) {
  const int tid = threadIdx.x;
  const int cl = tid >> 2;          // channel within block
  const int sg = tid & 3;           // state group: states sg*4 .. sg*4+3
  const int c = blockIdx.x * 64 + cl;
  const int b = blockIdx.y;
  const int ch = blockIdx.z;
  float a2[4];
#pragma unroll
  for (int j = 0; j < 4; ++j) a2[j] = -__expf(A_log[sg * 4 + j]) * LOG2E;
  float h[4] = {0.f, 0.f, 0.f, 0.f};
  float sumd = 0.f;
  const long base = (long)b * SEQ + (long)ch * CHUNK;
  for (int t = 0; t < CHUNK; ++t) {
    const long m = base + t;
    const float d = dlt[m * 1536 + c];
    const float du = d * uf[m * 1536 + c];
    sumd += d;
    const f32x4 Bv = *(const f32x4*)&Bm[m * 16 + sg * 4];
#pragma unroll
    for (int j = 0; j < 4; ++j) {
      const float e = exp2f(a2[j] * d);
      h[j] = e * h[j] + du * Bv[j];
    }
  }
  const long sb = (((long)b * NCHUNK + ch) * NST + sg * 4) * 1536 + c;
#pragma unroll
  for (int j = 0; j < 4; ++j) {
    Q[sb + (long)j * 1536] = h[j];
    P[sb + (long)j * 1536] = exp2f(a2[j] * sumd);
  }
}

// ---------------- scan phase B: serial combine over chunks (hs aliases P) -------
__global__ __launch_bounds__(256)
void scan_phaseB(float* __restrict__ P, const float* __restrict__ Q) {
  const long g = (long)blockIdx.x * 256 + threadIdx.x;   // BATCH*NST*INNER
  const int c = (int)(g % 1536);
  const int n = (int)((g / 1536) % NST);
  const int b = (int)(g / (1536 * NST));
  float h = 0.f;
  for (int ch = 0; ch < NCHUNK; ++ch) {
    const long idx = (((long)b * NCHUNK + ch) * NST + n) * 1536 + c;
    const float p = P[idx];
    const float q = Q[idx];
    P[idx] = h;              // hs written in place of P (read-before-write)
    h = p * h + q;
  }
}

// ---------------- scan phase C: replay with true h_start, emit ys bf16 ----------
__global__ __launch_bounds__(256)
void scan_phaseC(const float* __restrict__ dlt, const float* __restrict__ uf,
                 const float* __restrict__ Bm, const float* __restrict__ Cm,
                 const float* __restrict__ A_log, const float* __restrict__ Dv,
                 const float* __restrict__ hs, u16* __restrict__ ys) {
  const int tid = threadIdx.x;
  const int cl = tid >> 2;
  const int sg = tid & 3;
  const int c = blockIdx.x * 64 + cl;
  const int b = blockIdx.y;
  const int ch = blockIdx.z;
  float a2[4];
#pragma unroll
  for (int j = 0; j < 4; ++j) a2[j] = -__expf(A_log[sg * 4 + j]) * LOG2E;
  float h[4];
  const long sb = (((long)b * NCHUNK + ch) * NST + sg * 4) * 1536 + c;
#pragma unroll
  for (int j = 0; j < 4; ++j) h[j] = hs[sb + (long)j * 1536];
  const float Dc = Dv[c];
  const long base = (long)b * SEQ + (long)ch * CHUNK;
  for (int t = 0; t < CHUNK; ++t) {
    const long m = base + t;
    const float d = dlt[m * 1536 + c];
    const float uu = uf[m * 1536 + c];
    const float du = d * uu;
    const f32x4 Bv = *(const f32x4*)&Bm[m * 16 + sg * 4];
    const f32x4 Cv = *(const f32x4*)&Cm[m * 16 + sg * 4];
    float y = (sg == 0) ? Dc * uu : 0.f;
#pragma unroll
    for (int j = 0; j < 4; ++j) {
      const float e = exp2f(a2[j] * d);
      h[j] = e * h[j] + du * Bv[j];
      y += h[j] * Cv[j];
    }
    // reduce across the 4 state-group lanes (same channel)
    y += __shfl_xor(y, 1);
    y += __shfl_xor(y, 2);
    if (sg == 0) ys[m * 1536 + c] = f2b(y);
  }
}

extern "C" void kernel_launch(void* const* d_in, const int* in_sizes, int n_in,
                              void* d_out, int out_size, void* d_ws, size_t ws_size,
                              hipStream_t stream) {
  const float* x     = (const float*)d_in[0];
  const float* nw    = (const float*)d_in[1];
  const float* nb    = (const float*)d_in[2];
  const float* W_in  = (const float*)d_in[3];
  const float* cw    = (const float*)d_in[4];
  const float* W_xp  = (const float*)d_in[5];
  const float* A_log = (const float*)d_in[6];
  const float* Dv    = (const float*)d_in[7];
  const float* W_so  = (const float*)d_in[8];
  const float* W_out = (const float*)d_in[9];
  float* out = (float*)d_out;

  char* w = (char*)d_ws;
  auto alloc = [&](size_t bytes) {
    char* p = w;
    w += (bytes + 255) & ~(size_t)255;
    return p;
  };
  u16*   xn    = (u16*)  alloc((size_t)MTOK * HID * 2);
  u16*   WtIn  = (u16*)  alloc((size_t)3072 * 768 * 2);
  float* xp    = (float*)alloc((size_t)MTOK * 3072 * 4);
  float* uf    = (float*)alloc((size_t)MTOK * 1536 * 4);
  u16*   ub    = (u16*)  alloc((size_t)MTOK * 1536 * 2);
  u16*   WtXp  = (u16*)  alloc((size_t)1664 * 1536 * 2);
  float* Bmv   = (float*)alloc((size_t)MTOK * 16 * 4);
  float* Cmv   = (float*)alloc((size_t)MTOK * 16 * 4);
  float* dlt   = (float*)alloc((size_t)MTOK * 1536 * 4);
  float* P     = (float*)alloc((size_t)BATCH * NCHUNK * NST * 1536 * 4);  // becomes hs
  float* Q     = (float*)alloc((size_t)BATCH * NCHUNK * NST * 1536 * 4);
  u16*   ys    = (u16*)  alloc((size_t)MTOK * 1536 * 2);
  u16*   WtSo  = (u16*)  alloc((size_t)1536 * 1536 * 2);
  u16*   zb    = (u16*)  alloc((size_t)MTOK * 1536 * 2);
  u16*   WtOut = (u16*)  alloc((size_t)768 * 1536 * 2);

  ln_kernel<<<MTOK, 256, 0, stream>>>(x, nw, nb, xn);
  transpose_cvt<<<dim3(3072 / 32, 768 / 32), dim3(32, 8), 0, stream>>>(W_in, WtIn, 768, 3072, 3072);
  transpose_cvt<<<dim3(1664 / 32, 1536 / 32), dim3(32, 8), 0, stream>>>(W_xp, WtXp, 1536, 1568, 1664);
  transpose_cvt<<<dim3(1536 / 32, 1536 / 32), dim3(32, 8), 0, stream>>>(W_so, WtSo, 1536, 1536, 1536);
  transpose_cvt<<<dim3(768 / 32, 1536 / 32), dim3(32, 8), 0, stream>>>(W_out, WtOut, 1536, 768, 768);

  gemm_bt<0><<<dim3(24, 32), 256, 0, stream>>>(xn, WtIn, xp, nullptr, nullptr, nullptr, nullptr, 768, 3072);
  conv_silu<<<dim3(6, MTOK), 256, 0, stream>>>(xp, cw, uf, ub);
  gemm_bt<1><<<dim3(13, 32), 256, 0, stream>>>(ub, WtXp, Bmv, Cmv, dlt, nullptr, nullptr, 1536, 1568);
  scan_phaseA<<<dim3(24, 2, NCHUNK), 256, 0, stream>>>(dlt, uf, Bmv, A_log, P, Q);
  scan_phaseB<<<192, 256, 0, stream>>>(P, Q);
  scan_phaseC<<<dim3(24, 2, NCHUNK), 256, 0, stream>>>(dlt, uf, Bmv, Cmv, A_log, Dv, P, ys);
  gemm_bt<2><<<dim3(12, 32), 256, 0, stream>>>(ys, WtSo, nullptr, nullptr, nullptr, zb, xp, 1536, 1536);
  gemm_bt<3><<<dim3(6, 32), 256, 0, stream>>>(zb, WtOut, out, nullptr, nullptr, nullptr, x, 1536, 768);
}

// Round 3
// 398.636 us; speedup vs baseline: 1.2585x; 1.0542x over previous
//
#include <hip/hip_runtime.h>
#include <cstdint>
#include <cmath>

#define HID 768
#define INNER 1536
#define NST 16
#define SEQ 2048
#define BATCH 2
#define MTOK 4096      // BATCH*SEQ
#define CHUNK 32
#define NCHUNK 64      // SEQ/CHUNK
#define LOG2E 1.44269504088896f

typedef unsigned short u16;
typedef __bf16 bf16x8 __attribute__((ext_vector_type(8)));
typedef float f32x4 __attribute__((ext_vector_type(4)));

__device__ __forceinline__ u16 f2b(float f) {
  union { float f; unsigned u; } a; a.f = f;
  unsigned r = a.u + 0x7FFFu + ((a.u >> 16) & 1u);
  return (u16)(r >> 16);
}

__device__ __forceinline__ void gl2lds16(const u16* g, u16* l) {
  __builtin_amdgcn_global_load_lds(
      (const __attribute__((address_space(1))) void*)g,
      (__attribute__((address_space(3))) void*)l, 16, 0, 0);
}

// ---------------- LayerNorm + cast to bf16 ----------------
__global__ __launch_bounds__(256)
void ln_kernel(const float* __restrict__ x, const float* __restrict__ w,
               const float* __restrict__ b, u16* __restrict__ xn) {
  const long row = blockIdx.x;
  const float* xr = x + row * HID;
  const int t = threadIdx.x;
  float v0 = xr[t], v1 = xr[t + 256], v2 = xr[t + 512];
  float s1 = v0 + v1 + v2;
  float s2 = v0 * v0 + v1 * v1 + v2 * v2;
#pragma unroll
  for (int o = 32; o > 0; o >>= 1) { s1 += __shfl_down(s1, o); s2 += __shfl_down(s2, o); }
  __shared__ float r1[4], r2[4];
  if ((t & 63) == 0) { r1[t >> 6] = s1; r2[t >> 6] = s2; }
  __syncthreads();
  s1 = r1[0] + r1[1] + r1[2] + r1[3];
  s2 = r2[0] + r2[1] + r2[2] + r2[3];
  const float mu = s1 * (1.f / HID);
  float var = s2 * (1.f / HID) - mu * mu;
  const float rs = rsqrtf(var + 1e-5f);
  xn[row * HID + t]       = f2b((v0 - mu) * rs * w[t]       + b[t]);
  xn[row * HID + t + 256] = f2b((v1 - mu) * rs * w[t + 256] + b[t + 256]);
  xn[row * HID + t + 512] = f2b((v2 - mu) * rs * w[t + 512] + b[t + 512]);
}

// ---------------- fp32 W[K][N] -> bf16 Wt[Npad][K] (transpose+convert, zero pad) ----
__global__ __launch_bounds__(256)
void transpose_cvt(const float* __restrict__ W, u16* __restrict__ Wt,
                   int K, int N, int Npad) {
  __shared__ float tb[32][33];
  const int tx = threadIdx.x, ty = threadIdx.y;
  const int n0 = blockIdx.x * 32, k0 = blockIdx.y * 32;
#pragma unroll
  for (int r = 0; r < 4; ++r) {
    int kk = k0 + ty + r * 8;
    int nn = n0 + tx;
    tb[ty + r * 8][tx] = (nn < N) ? W[(long)kk * N + nn] : 0.f;
  }
  __syncthreads();
#pragma unroll
  for (int r = 0; r < 4; ++r) {
    int nn = n0 + ty + r * 8;
    int kk = k0 + tx;
    Wt[(long)nn * K + kk] = f2b(tb[tx][ty + r * 8]);
  }
}

// ---------------- GEMM: A[M][K] bf16 row-major, Bt[N][K] bf16, BMxBN tile ------
// 256 threads = 4 waves in 2x2; wave tile (BM/2)x(BN/2); BK=32.
// EPI 0: C0[row*3072+col] = v
// EPI 1: col<16 -> Bm, col<32 -> Cm, col<Nstore -> delta=softplus
// EPI 2: zb = bf16(v * silu(gate)), gate = E0[row*3072+1536+col]
// EPI 3: C0[row*768+col] = v + E0[row*768+col]
template <int BM, int BN, int EPI>
__global__ __launch_bounds__(256)
void gemm_bt(const u16* __restrict__ A, const u16* __restrict__ Bt,
             float* __restrict__ C0, float* __restrict__ C1, float* __restrict__ C2,
             u16* __restrict__ Cb, const float* __restrict__ E0,
             int K, int Nstore) {
  constexpr int WTM = BM / 2;       // wave tile M
  constexpr int WTN = BN / 2;       // wave tile N
  constexpr int FI = WTM / 16;      // A frags per wave
  constexpr int FJ = WTN / 16;      // B frags per wave
  __shared__ u16 As[BM * 32];
  __shared__ u16 Bs[BN * 32];
  const int tid = threadIdx.x;
  const int lane = tid & 63;
  const int wave = tid >> 6;
  const int wm = wave >> 1, wn = wave & 1;
  const int l16 = lane & 15, l4 = lane >> 4;
  const long bm = (long)blockIdx.y * BM;
  const long bn = (long)blockIdx.x * BN;

  f32x4 acc[FI][FJ] = {};

  const int r0 = tid >> 2;          // 0..63
  const int kg = (tid & 3) * 8;     // 0,8,16,24

  for (int k0 = 0; k0 < K; k0 += 32) {
#pragma unroll
    for (int q = 0; q < BM / 64; ++q)
      gl2lds16(A + (bm + r0 + q * 64) * K + kg + k0, As + ((q * 256 + tid) * 8));
#pragma unroll
    for (int q = 0; q < BN / 64; ++q)
      gl2lds16(Bt + (bn + r0 + q * 64) * K + kg + k0, Bs + ((q * 256 + tid) * 8));
    __syncthreads();
    bf16x8 af[FI], bfr[FJ];
#pragma unroll
    for (int i = 0; i < FI; ++i)
      af[i] = *(const bf16x8*)&As[(wm * WTM + i * 16 + l16) * 32 + l4 * 8];
#pragma unroll
    for (int j = 0; j < FJ; ++j)
      bfr[j] = *(const bf16x8*)&Bs[(wn * WTN + j * 16 + l16) * 32 + l4 * 8];
#pragma unroll
    for (int i = 0; i < FI; ++i)
#pragma unroll
      for (int j = 0; j < FJ; ++j)
        acc[i][j] = __builtin_amdgcn_mfma_f32_16x16x32_bf16(af[i], bfr[j], acc[i][j], 0, 0, 0);
    __syncthreads();
  }

#pragma unroll
  for (int i = 0; i < FI; ++i) {
    const long rr = bm + wm * WTM + i * 16 + l4 * 4;
#pragma unroll
    for (int j = 0; j < FJ; ++j) {
      const int cc = (int)bn + wn * WTN + j * 16 + l16;
#pragma unroll
      for (int r = 0; r < 4; ++r) {
        const long row = rr + r;
        const float v = acc[i][j][r];
        if (EPI == 0) {
          C0[row * 3072 + cc] = v;
        } else if (EPI == 1) {
          if (cc < 16) C0[row * 16 + cc] = v;
          else if (cc < 32) C1[row * 16 + (cc - 16)] = v;
          else if (cc < Nstore) {
            float sp = (v > 20.f) ? v : log1pf(__expf(v));
            C2[row * 1536 + (cc - 32)] = sp;
          }
        } else if (EPI == 2) {
          float g = E0[row * 3072 + 1536 + cc];
          float s = g / (1.f + __expf(-g));
          Cb[row * 1536 + cc] = f2b(v * s);
        } else {
          C0[row * 768 + cc] = v + E0[row * 768 + cc];
        }
      }
    }
  }
}

// ---------------- depthwise causal conv(K=4) + SiLU ----------------
__global__ __launch_bounds__(256)
void conv_silu(const float* __restrict__ xp, const float* __restrict__ cw,
               float* __restrict__ uf, u16* __restrict__ ub) {
  const int c = blockIdx.x * 256 + threadIdx.x;
  const long m = blockIdx.y;
  const int t = (int)(m & (SEQ - 1));
  const float w0 = cw[c * 4 + 0], w1 = cw[c * 4 + 1], w2 = cw[c * 4 + 2], w3 = cw[c * 4 + 3];
  float acc = w3 * xp[m * 3072 + c];
  if (t >= 1) acc += w2 * xp[(m - 1) * 3072 + c];
  if (t >= 2) acc += w1 * xp[(m - 2) * 3072 + c];
  if (t >= 3) acc += w0 * xp[(m - 3) * 3072 + c];
  const float s = acc / (1.f + __expf(-acc));
  uf[m * 1536 + c] = s;
  ub[m * 1536 + c] = f2b(s);
}

// ---------------- scan phase A: per-chunk (P, Q) from h=0, 4 states/thread ------
__global__ __launch_bounds__(256)
void scan_phaseA(const float* __restrict__ dlt, const float* __restrict__ uf,
                 const float* __restrict__ Bm, const float* __restrict__ A_log,
                 float* __restrict__ P, float* __restrict__ Q) {
  const int tid = threadIdx.x;
  const int cl = tid >> 2;
  const int sg = tid & 3;
  const int c = blockIdx.x * 64 + cl;
  const int b = blockIdx.y;
  const int ch = blockIdx.z;
  float a2[4];
#pragma unroll
  for (int j = 0; j < 4; ++j) a2[j] = -__expf(A_log[sg * 4 + j]) * LOG2E;
  float h[4] = {0.f, 0.f, 0.f, 0.f};
  float sumd = 0.f;
  const long base = (long)b * SEQ + (long)ch * CHUNK;
  for (int t = 0; t < CHUNK; ++t) {
    const long m = base + t;
    const float d = dlt[m * 1536 + c];
    const float du = d * uf[m * 1536 + c];
    sumd += d;
    const f32x4 Bv = *(const f32x4*)&Bm[m * 16 + sg * 4];
#pragma unroll
    for (int j = 0; j < 4; ++j) {
      const float e = exp2f(a2[j] * d);
      h[j] = e * h[j] + du * Bv[j];
    }
  }
  const long sb = (((long)b * NCHUNK + ch) * NST + sg * 4) * 1536 + c;
#pragma unroll
  for (int j = 0; j < 4; ++j) {
    Q[sb + (long)j * 1536] = h[j];
    P[sb + (long)j * 1536] = exp2f(a2[j] * sumd);
  }
}

// ---------------- scan phase B: serial combine over chunks (hs aliases P) -------
__global__ __launch_bounds__(256)
void scan_phaseB(float* __restrict__ P, const float* __restrict__ Q) {
  const long g = (long)blockIdx.x * 256 + threadIdx.x;   // BATCH*NST*INNER
  const int c = (int)(g % 1536);
  const int n = (int)((g / 1536) % NST);
  const int b = (int)(g / (1536 * NST));
  float h = 0.f;
  for (int ch = 0; ch < NCHUNK; ++ch) {
    const long idx = (((long)b * NCHUNK + ch) * NST + n) * 1536 + c;
    const float p = P[idx];
    const float q = Q[idx];
    P[idx] = h;              // hs written in place of P (read-before-write)
    h = p * h + q;
  }
}

// ---------------- scan phase C: replay with true h_start, emit ys bf16 ----------
__global__ __launch_bounds__(256)
void scan_phaseC(const float* __restrict__ dlt, const float* __restrict__ uf,
                 const float* __restrict__ Bm, const float* __restrict__ Cm,
                 const float* __restrict__ A_log, const float* __restrict__ Dv,
                 const float* __restrict__ hs, u16* __restrict__ ys) {
  const int tid = threadIdx.x;
  const int cl = tid >> 2;
  const int sg = tid & 3;
  const int c = blockIdx.x * 64 + cl;
  const int b = blockIdx.y;
  const int ch = blockIdx.z;
  float a2[4];
#pragma unroll
  for (int j = 0; j < 4; ++j) a2[j] = -__expf(A_log[sg * 4 + j]) * LOG2E;
  float h[4];
  const long sb = (((long)b * NCHUNK + ch) * NST + sg * 4) * 1536 + c;
#pragma unroll
  for (int j = 0; j < 4; ++j) h[j] = hs[sb + (long)j * 1536];
  const float Dc = Dv[c];
  const long base = (long)b * SEQ + (long)ch * CHUNK;
  for (int t = 0; t < CHUNK; ++t) {
    const long m = base + t;
    const float d = dlt[m * 1536 + c];
    const float uu = uf[m * 1536 + c];
    const float du = d * uu;
    const f32x4 Bv = *(const f32x4*)&Bm[m * 16 + sg * 4];
    const f32x4 Cv = *(const f32x4*)&Cm[m * 16 + sg * 4];
    float y = (sg == 0) ? Dc * uu : 0.f;
#pragma unroll
    for (int j = 0; j < 4; ++j) {
      const float e = exp2f(a2[j] * d);
      h[j] = e * h[j] + du * Bv[j];
      y += h[j] * Cv[j];
    }
    y += __shfl_xor(y, 1);
    y += __shfl_xor(y, 2);
    if (sg == 0) ys[m * 1536 + c] = f2b(y);
  }
}

extern "C" void kernel_launch(void* const* d_in, const int* in_sizes, int n_in,
                              void* d_out, int out_size, void* d_ws, size_t ws_size,
                              hipStream_t stream) {
  const float* x     = (const float*)d_in[0];
  const float* nw    = (const float*)d_in[1];
  const float* nb    = (const float*)d_in[2];
  const float* W_in  = (const float*)d_in[3];
  const float* cw    = (const float*)d_in[4];
  const float* W_xp  = (const float*)d_in[5];
  const float* A_log = (const float*)d_in[6];
  const float* Dv    = (const float*)d_in[7];
  const float* W_so  = (const float*)d_in[8];
  const float* W_out = (const float*)d_in[9];
  float* out = (float*)d_out;

  char* w = (char*)d_ws;
  auto alloc = [&](size_t bytes) {
    char* p = w;
    w += (bytes + 255) & ~(size_t)255;
    return p;
  };
  u16*   xn    = (u16*)  alloc((size_t)MTOK * HID * 2);
  u16*   WtIn  = (u16*)  alloc((size_t)3072 * 768 * 2);
  float* xp    = (float*)alloc((size_t)MTOK * 3072 * 4);
  float* uf    = (float*)alloc((size_t)MTOK * 1536 * 4);
  u16*   ub    = (u16*)  alloc((size_t)MTOK * 1536 * 2);
  u16*   WtXp  = (u16*)  alloc((size_t)1664 * 1536 * 2);
  float* Bmv   = (float*)alloc((size_t)MTOK * 16 * 4);
  float* Cmv   = (float*)alloc((size_t)MTOK * 16 * 4);
  float* dlt   = (float*)alloc((size_t)MTOK * 1536 * 4);
  float* P     = (float*)alloc((size_t)BATCH * NCHUNK * NST * 1536 * 4);  // becomes hs
  float* Q     = (float*)alloc((size_t)BATCH * NCHUNK * NST * 1536 * 4);
  u16*   ys    = (u16*)  alloc((size_t)MTOK * 1536 * 2);
  u16*   WtSo  = (u16*)  alloc((size_t)1536 * 1536 * 2);
  u16*   zb    = (u16*)  alloc((size_t)MTOK * 1536 * 2);
  u16*   WtOut = (u16*)  alloc((size_t)768 * 1536 * 2);

  ln_kernel<<<MTOK, 256, 0, stream>>>(x, nw, nb, xn);
  transpose_cvt<<<dim3(3072 / 32, 768 / 32), dim3(32, 8), 0, stream>>>(W_in, WtIn, 768, 3072, 3072);
  transpose_cvt<<<dim3(1664 / 32, 1536 / 32), dim3(32, 8), 0, stream>>>(W_xp, WtXp, 1536, 1568, 1664);
  transpose_cvt<<<dim3(1536 / 32, 1536 / 32), dim3(32, 8), 0, stream>>>(W_so, WtSo, 1536, 1536, 1536);
  transpose_cvt<<<dim3(768 / 32, 1536 / 32), dim3(32, 8), 0, stream>>>(W_out, WtOut, 1536, 768, 768);

  // gemm0: 4096x3072, K=768  -> 128x128 tile, 24x32 = 768 blocks (3/CU)
  gemm_bt<128, 128, 0><<<dim3(24, 32), 256, 0, stream>>>(xn, WtIn, xp, nullptr, nullptr, nullptr, nullptr, 768, 3072);
  conv_silu<<<dim3(6, MTOK), 256, 0, stream>>>(xp, cw, uf, ub);
  // gemm1: 4096x1664, K=1536 -> 128x64 tile, 26x32 = 832 blocks
  gemm_bt<128, 64, 1><<<dim3(26, 32), 256, 0, stream>>>(ub, WtXp, Bmv, Cmv, dlt, nullptr, nullptr, 1536, 1568);
  scan_phaseA<<<dim3(24, 2, NCHUNK), 256, 0, stream>>>(dlt, uf, Bmv, A_log, P, Q);
  scan_phaseB<<<192, 256, 0, stream>>>(P, Q);
  scan_phaseC<<<dim3(24, 2, NCHUNK), 256, 0, stream>>>(dlt, uf, Bmv, Cmv, A_log, Dv, P, ys);
  // gemm2: 4096x1536, K=1536 -> 128x64 tile, 24x32 = 768 blocks
  gemm_bt<128, 64, 2><<<dim3(24, 32), 256, 0, stream>>>(ys, WtSo, nullptr, nullptr, nullptr, zb, xp, 1536, 1536);
  // gemm3: 4096x768,  K=1536 -> 64x64 tile, 12x64 = 768 blocks
  gemm_bt<64, 64, 3><<<dim3(12, 64), 256, 0, stream>>>(zb, WtOut, out, nullptr, nullptr, nullptr, x, 1536, 768);
}